// Round 15
// baseline (137.979 us; speedup 1.0000x reference)
//
#include <hip/hip_runtime.h>
#include <stdint.h>

typedef short bf16x8 __attribute__((ext_vector_type(8)));
typedef float f32x4 __attribute__((ext_vector_type(4)));
typedef float f32x16 __attribute__((ext_vector_type(16)));
typedef unsigned short u16;

#define MFMA_BF16 __builtin_amdgcn_mfma_f32_16x16x32_bf16
#define MFMA32 __builtin_amdgcn_mfma_f32_32x32x16_bf16
#define LOG2E 1.44269504088896f

#if __has_builtin(__builtin_amdgcn_exp2f)
#define EXP2(x) __builtin_amdgcn_exp2f(x)
#else
#define EXP2(x) exp2f(x)
#endif

static __device__ __forceinline__ u16 f2bf(float x) {
  union { float f; unsigned u; } v; v.f = x;
  unsigned r = v.u + 0x7fffu + ((v.u >> 16) & 1u);
  return (u16)(r >> 16);
}
static __device__ __forceinline__ float bf2f(u16 h) {
  union { unsigned u; float f; } v; v.u = ((unsigned)h) << 16; return v.f;
}
static __device__ __forceinline__ unsigned cvt_pk_bf16(float lo, float hi) {
  unsigned r;
  asm("v_cvt_pk_bf16_f32 %0, %1, %2" : "=v"(r) : "v"(lo), "v"(hi));
  return r;
}
static __device__ __forceinline__ void gld_lds16(const u16* g, u16* l) {
  __builtin_amdgcn_global_load_lds(
      (const __attribute__((address_space(1))) void*)g,
      (__attribute__((address_space(3))) void*)l, 16, 0, 0);
}

// ---------------- fused prep: cast | wtrans(w_qkv) | wtrans(w_out) | ropetab ----------------
__global__ __launch_bounds__(256) void k_prep(const float* __restrict__ x,
                                              u16* __restrict__ y,
                                              const float* __restrict__ wqkv,
                                              u16* __restrict__ wqkvT,
                                              const float* __restrict__ wout,
                                              u16* __restrict__ woutT,
                                              float2* __restrict__ tab) {
  const int bid = blockIdx.x;
  const int tid = threadIdx.x;
  if (bid < 2048) {
    int i = bid * 256 + tid;
    const float4* p = (const float4*)x;
    float4 a = p[i * 2], b = p[i * 2 + 1];
    ushort4 o0, o1;
    o0.x = f2bf(a.x); o0.y = f2bf(a.y); o0.z = f2bf(a.z); o0.w = f2bf(a.w);
    o1.x = f2bf(b.x); o1.y = f2bf(b.y); o1.z = f2bf(b.z); o1.w = f2bf(b.w);
    ushort4* q = (ushort4*)y;
    q[i * 2] = o0; q[i * 2 + 1] = o1;
  } else if (bid < 3584) {
    int r = bid - 2048;
    int n = (r % 12) * 256 + tid;
    int k0 = (r / 12) * 8;
    u16 o[8];
#pragma unroll
    for (int j = 0; j < 8; j++) o[j] = f2bf(wqkv[(size_t)(k0 + j) * 3072 + n]);
    *(uint4*)&wqkvT[(size_t)n * 1024 + k0] = *(const uint4*)o;
  } else if (bid < 4096) {
    int r = bid - 3584;
    int n = (r % 4) * 256 + tid;
    int k0 = (r / 4) * 8;
    u16 o[8];
#pragma unroll
    for (int j = 0; j < 8; j++) o[j] = f2bf(wout[(size_t)(k0 + j) * 1024 + n]);
    *(uint4*)&woutT[(size_t)n * 1024 + k0] = *(const uint4*)o;
  } else {
    int i = (bid - 4096) * 256 + tid;  // 65536 = 2048*32
    int n = i >> 5, f = i & 31;
    float inv = exp2f(-(float)f * (13.287712379549449f / 32.f));
    float fr = (float)n * inv;
    float s, c;
    sincosf(fr, &s, &c);
    float2 cs; cs.x = c; cs.y = s;
    tab[i] = cs;
  }
}

// ---------------- GEMM: C[M][N] = A[M][K] * Bt[N][K]^T + bias (R9 form) ----------------
template <int OUT_BF16>
__global__ __launch_bounds__(256, 2) void k_gemm(const u16* __restrict__ A,
                                                 const u16* __restrict__ Bt,
                                                 const float* __restrict__ bias,
                                                 void* __restrict__ Cp,
                                                 int M, int N, int K) {
  __shared__ u16 As[128 * 64];
  __shared__ u16 Bs[128 * 64];
  const int tid = threadIdx.x;
  const int lane = tid & 63;
  const int wid = tid >> 6;
  const int wm = wid >> 1, wn = wid & 1;
  const int m0 = blockIdx.x * 128, n0 = blockIdx.y * 128;

  const int sr = tid >> 3;
  const int sc = tid & 7;
  const int scsw = sc ^ (sr & 7);
  const u16* ga = A + (size_t)(m0 + sr) * K + (scsw << 3);
  const u16* gb = Bt + (size_t)(n0 + sr) * K + (scsw << 3);

  const int ar = wm * 64 + (lane & 15);
  const int br = wn * 64 + (lane & 15);
  const int cs0 = lane >> 4;

  f32x4 acc[4][4] = {};

  for (int k0 = 0; k0 < K; k0 += 64) {
    __syncthreads();
#pragma unroll
    for (int i = 0; i < 4; i++)
      gld_lds16(ga + k0 + i * (32 * K), &As[((tid & ~63) + 256 * i) * 8]);
#pragma unroll
    for (int i = 0; i < 4; i++)
      gld_lds16(gb + k0 + i * (32 * K), &Bs[((tid & ~63) + 256 * i) * 8]);
    __syncthreads();
#pragma unroll
    for (int kk = 0; kk < 2; kk++) {
      bf16x8 af[4], bfr[4];
#pragma unroll
      for (int mi = 0; mi < 4; mi++)
        af[mi] = *(const bf16x8*)&As[(ar + mi * 16) * 64 +
                                     (((kk * 4 + cs0) ^ (ar & 7)) << 3)];
#pragma unroll
      for (int ni = 0; ni < 4; ni++)
        bfr[ni] = *(const bf16x8*)&Bs[(br + ni * 16) * 64 +
                                      (((kk * 4 + cs0) ^ (br & 7)) << 3)];
#pragma unroll
      for (int mi = 0; mi < 4; mi++)
#pragma unroll
        for (int ni = 0; ni < 4; ni++)
          acc[mi][ni] = MFMA_BF16(af[mi], bfr[ni], acc[mi][ni], 0, 0, 0);
    }
  }

  const int crow0 = m0 + wm * 64 + ((lane >> 4) << 2);
  const int ccol0 = n0 + wn * 64 + (lane & 15);
#pragma unroll
  for (int ni = 0; ni < 4; ni++) {
    float bv = bias[ccol0 + ni * 16];
#pragma unroll
    for (int mi = 0; mi < 4; mi++) {
#pragma unroll
      for (int r = 0; r < 4; r++) {
        float v = acc[mi][ni][r] + bv;
        size_t idx = (size_t)(crow0 + mi * 16 + r) * N + ccol0 + ni * 16;
        if (OUT_BF16) ((u16*)Cp)[idx] = f2bf(v);
        else ((float*)Cp)[idx] = v;
      }
    }
  }
}

// ---------------- fused norm/rope + v-transpose ----------------
__global__ __launch_bounds__(256) void k_nv(const u16* __restrict__ qkv,
                                            const float* __restrict__ qscale,
                                            const float* __restrict__ kscale,
                                            const float2* __restrict__ tab,
                                            u16* __restrict__ Qb,
                                            u16* __restrict__ Kb,
                                            u16* __restrict__ Vt) {
  __shared__ __align__(16) u16 sm[64 * 72];
  const int t = threadIdx.x;
  if (blockIdx.x < 4096) {
    const int row = blockIdx.x;  // b*2048+n
    const int b = row >> 11, n = row & 2047;
    float* qn = (float*)sm;
    float* kn = qn + 1024;
    __shared__ float redq[4], redk[4];

    ushort4 q4 = *(const ushort4*)&qkv[(size_t)row * 3072 + t * 4];
    ushort4 k4 = *(const ushort4*)&qkv[(size_t)row * 3072 + 1024 + t * 4];
    float qv[4] = {bf2f(q4.x), bf2f(q4.y), bf2f(q4.z), bf2f(q4.w)};
    float kv[4] = {bf2f(k4.x), bf2f(k4.y), bf2f(k4.z), bf2f(k4.w)};
    float sq = 0.f, sk = 0.f;
#pragma unroll
    for (int j = 0; j < 4; j++) { sq += qv[j] * qv[j]; sk += kv[j] * kv[j]; }
#pragma unroll
    for (int o = 1; o < 64; o <<= 1) {
      sq += __shfl_xor(sq, o);
      sk += __shfl_xor(sk, o);
    }
    if ((t & 63) == 0) { redq[t >> 6] = sq; redk[t >> 6] = sk; }

    const int j0 = t * 4;
    const int d0 = j0 & 63;
    float2 cs[4];
    {
      const float2* tb = tab + n * 32 + (d0 & 31);
      *(float4*)&cs[0] = *(const float4*)&tb[0];
      *(float4*)&cs[2] = *(const float4*)&tb[2];
    }
    __syncthreads();
    float rq = rsqrtf((redq[0] + redq[1] + redq[2] + redq[3]) * (1.f / 1024.f) + 1e-6f);
    float rk = rsqrtf((redk[0] + redk[1] + redk[2] + redk[3]) * (1.f / 1024.f) + 1e-6f);
#pragma unroll
    for (int j = 0; j < 4; j++) {
      int jj = t * 4 + j;
      qn[jj] = qv[j] * rq * qscale[jj];
      kn[jj] = kv[j] * rk * kscale[jj];
    }
    __syncthreads();
    const int h = j0 >> 6;
    u16 qo[4], ko[4];
#pragma unroll
    for (int j = 0; j < 4; j++) {
      int jj = j0 + j;
      int dd = d0 + j;
      float c = cs[j].x, s = cs[j].y;
      float oq, ok;
      if (dd < 32) {
        oq = qn[jj] * c - qn[jj + 32] * s;
        ok = kn[jj] * c - kn[jj + 32] * s;
      } else {
        oq = qn[jj] * c + qn[jj - 32] * s;
        ok = kn[jj] * c + kn[jj - 32] * s;
      }
      qo[j] = f2bf(oq * (0.125f * LOG2E));
      ko[j] = f2bf(ok);
    }
    const size_t base = ((size_t)(b * 16 + h) * 2048 + n) * 64 + d0;
    *(ushort4*)&Qb[base] = *(const ushort4*)qo;
    *(ushort4*)&Kb[base] = *(const ushort4*)ko;
  } else {
    const int r = blockIdx.x - 4096;
    const int bh = r >> 5;
    const int b = bh >> 4, h = bh & 15;
    const int n0 = (r & 31) * 64;
    u16 (*tile)[72] = (u16(*)[72])sm;
#pragma unroll
    for (int i = 0; i < 2; i++) {
      int rr = (t >> 3) + 32 * i;
      int c = t & 7;
      uint4 v = *(const uint4*)&qkv[((size_t)(b * 2048 + n0 + rr)) * 3072 + 2048 + h * 64 + c * 8];
      *(uint4*)&tile[rr][c * 8] = v;
    }
    __syncthreads();
#pragma unroll
    for (int i = 0; i < 2; i++) {
      int dr = (t >> 3) + 32 * i;
      int c = t & 7;
      u16 vals[8];
#pragma unroll
      for (int j = 0; j < 8; j++) vals[j] = tile[c * 8 + j][dr];
      *(uint4*)&Vt[((size_t)bh * 64 + dr) * 2048 + n0 + c * 8] = *(const uint4*)vals;
    }
  }
}

// ---------------- flash attention (v15 = R13 geometry + natural VGPR) ----------------
// BQ=64, KVBLK=32, 8 waves = 2 q-subs x 4 kv-groups, grp g owns tiles 4s+g
// with a dedicated 8KB buffer (32KB LDS). Grid 32x32 = 1024 blocks -> 4/CU;
// launch_bounds(512,4) leaves VGPR natural (~52, R14-measured) -> no spill,
// 8 waves/SIMD fit -> target 32 waves/CU. R13 proved this geometry correct
// AND that occupancy reaches 83%; R13's only failure was forcing VGPR<=64.
__global__ __launch_bounds__(512, 4) void k_attn(const u16* __restrict__ Qb,
                                                 const u16* __restrict__ Kb,
                                                 const u16* __restrict__ Vt,
                                                 u16* __restrict__ Ob) {
  const int bh = blockIdx.y;
  const int q0 = blockIdx.x * 64;
  const int t = threadIdx.x, lane = t & 63, wid = t >> 6;
  const int grp = wid >> 1, sub = wid & 1;
  const int q = lane & 31, hi = lane >> 5;

  __shared__ __align__(16) u16 smem[16384];   // 32 KB: Ks[4][2048] | Vs[4][2048]
  __shared__ float lA[64], lB[64], lC[64];
  u16* Ks = smem;
  u16* Vs = smem + 8192;

  const u16* Qg = Qb + (size_t)bh * 2048 * 64;
  const u16* Kg = Kb + (size_t)bh * 2048 * 64;
  const u16* Vg = Vt + (size_t)bh * 64 * 2048;

  // Q fragments (B-operand): col=q, k = kk*16 + hi*8 + j
  bf16x8 qf[4];
  {
    const u16* qrow = Qg + (size_t)(q0 + sub * 32 + q) * 64;
#pragma unroll
    for (int kk = 0; kk < 4; kk++)
      qf[kk] = *(const bf16x8*)&qrow[kk * 16 + hi * 8];
  }

  f32x16 ot[2] = {};   // O^T: ot[dt][r] = O[q][d = dt*32 + (r&3)+8*(r>>2)+4*hi]
  float lacc[4] = {0.f, 0.f, 0.f, 0.f};

  // staging roles: waves 0-3 (t<256) stage K tiles; waves 4-7 stage V tiles.
  const int t2 = t & 255;
  const bool isK = wid < 4;
  const u16* gsrc = isK
      ? Kg + (size_t)(t2 >> 3) * 64 + (((t2 & 7) ^ ((t2 >> 3) & 7)) << 3)
      : Vg + (size_t)(t2 >> 2) * 2048 + (((t2 & 3) ^ ((t2 >> 2) & 3)) << 3);
  const size_t gstep = isK ? 2048 : 32;   // per-tile advance in u16
  u16* lbase = (isK ? Ks : Vs) + (t2 & ~63) * 8;

#define STAGE(tile) gld_lds16(gsrc + (size_t)(tile) * gstep, lbase + ((tile) & 3) * 2048)

  // prologue: tiles 0..3 (1 load/thread each)
  STAGE(0); STAGE(1); STAGE(2); STAGE(3);

  const u16* Kc = &Ks[grp * 2048];
  const u16* Vc = &Vs[grp * 2048];

  for (int s = 0; s < 16; ++s) {
    asm volatile("s_waitcnt vmcnt(0)" ::: "memory");
    asm volatile("s_barrier" ::: "memory");

    // QK^T swapped: sv[r] = S[kv = (r&3)+8*(r>>2)+4*hi][q], tile 4s+grp
    f32x16 sv = {};
#pragma unroll
    for (int kk = 0; kk < 4; kk++) {
      bf16x8 kf = *(const bf16x8*)&Kc[q * 64 + (((kk * 2 + hi) ^ (q & 7)) << 3)];
      __builtin_amdgcn_s_setprio(1);
      sv = MFMA32(kf, qf[kk], sv, 0, 0, 0);
      __builtin_amdgcn_s_setprio(0);
    }

    // softmax: p = exp2(s) (scale+log2e pre-folded into Q)
    unsigned w[8];
#pragma unroll
    for (int i = 0; i < 8; i++) {
      float p0 = EXP2(sv[2 * i]);
      float p1 = EXP2(sv[2 * i + 1]);
      lacc[i & 3] += p0 + p1;
      w[i] = cvt_pk_bf16(p0, p1);
    }

    // PV: O^T += V^T P^T; B-frag via shfl_xor(32) cross-half exchange
#pragma unroll
    for (int ks = 0; ks < 2; ks++) {
      const int i0 = ks * 4;
      unsigned xs0 = hi ? w[i0 + 0] : w[i0 + 2];
      unsigned xs1 = hi ? w[i0 + 1] : w[i0 + 3];
      unsigned y0 = __shfl_xor(xs0, 32);
      unsigned y1 = __shfl_xor(xs1, 32);
      union { unsigned u[4]; bf16x8 v; } pf;
      pf.u[0] = hi ? y0 : w[i0 + 0];
      pf.u[1] = hi ? y1 : w[i0 + 1];
      pf.u[2] = hi ? w[i0 + 2] : y0;
      pf.u[3] = hi ? w[i0 + 3] : y1;
#pragma unroll
      for (int dt = 0; dt < 2; dt++) {
        const int vr = dt * 32 + q;
        bf16x8 va = *(const bf16x8*)&Vc[vr * 32 + (((ks * 2 + hi) ^ (vr & 3)) << 3)];
        __builtin_amdgcn_s_setprio(1);
        ot[dt] = MFMA32(va, pf.v, ot[dt], 0, 0, 0);
        __builtin_amdgcn_s_setprio(0);
      }
    }

    asm volatile("s_barrier" ::: "memory");  // all waves done reading buffers
    if (s < 15) { STAGE(4 * s + 4); STAGE(4 * s + 5); STAGE(4 * s + 6); STAGE(4 * s + 7); }
  }
#undef STAGE

  float lsum = (lacc[0] + lacc[1]) + (lacc[2] + lacc[3]);
  lsum += __shfl_xor(lsum, 32);   // combine hi halves (same q-row)

  // 4-way kv-split combine, phased LDS tree.
  __syncthreads();
  float* slotA = (float*)smem;             // [64][64] f32 = 16 KB
  float* slotB = (float*)(smem + 8192);    // [64][64] f32 = 16 KB
  const int row = sub * 32 + q;

#define DUMP(slot, lv)                                                        \
  do {                                                                        \
    float* ob = (slot) + row * 64;                                            \
    _Pragma("unroll")                                                         \
    for (int dt = 0; dt < 2; dt++)                                            \
      _Pragma("unroll")                                                       \
      for (int g = 0; g < 4; g++) {                                           \
        float4 v4 = {ot[dt][4 * g], ot[dt][4 * g + 1], ot[dt][4 * g + 2],     \
                     ot[dt][4 * g + 3]};                                      \
        *(float4*)&ob[dt * 32 + 8 * g + 4 * hi] = v4;                         \
      }                                                                       \
    if (lane < 32) (lv)[row] = lsum;                                          \
  } while (0)

#define ACCUM(slot, lv)                                                       \
  do {                                                                        \
    const float* ob = (slot) + row * 64;                                      \
    _Pragma("unroll")                                                         \
    for (int dt = 0; dt < 2; dt++)                                            \
      _Pragma("unroll")                                                       \
      for (int g = 0; g < 4; g++) {                                           \
        float4 v4 = *(const float4*)&ob[dt * 32 + 8 * g + 4 * hi];            \
        ot[dt][4 * g + 0] += v4.x;                                            \
        ot[dt][4 * g + 1] += v4.y;                                            \
        ot[dt][4 * g + 2] += v4.z;                                            \
        ot[dt][4 * g + 3] += v4.w;                                            \
      }                                                                       \
    lsum += (lv)[row];                                                        \
  } while (0)

  if (grp == 1) DUMP(slotA, lA);
  if (grp == 3) DUMP(slotB, lB);
  __syncthreads();
  if (grp == 0) ACCUM(slotA, lA);
  if (grp == 2) ACCUM(slotB, lB);
  __syncthreads();
  if (grp == 2) DUMP(slotA, lC);
  __syncthreads();
  if (grp == 0) {
    ACCUM(slotA, lC);
    const float invl = 1.f / lsum;
    const int b = bh >> 4, h = bh & 15;
    const int rowq = q0 + row;
    u16* orow = Ob + (size_t)(b * 2048 + rowq) * 1024 + h * 64;
#pragma unroll
    for (int dt = 0; dt < 2; dt++)
#pragma unroll
      for (int g = 0; g < 4; g++) {
        u16 o4[4];
        o4[0] = f2bf(ot[dt][4 * g + 0] * invl);
        o4[1] = f2bf(ot[dt][4 * g + 1] * invl);
        o4[2] = f2bf(ot[dt][4 * g + 2] * invl);
        o4[3] = f2bf(ot[dt][4 * g + 3] * invl);
        *(ushort4*)&orow[dt * 32 + 8 * g + 4 * hi] = *(const ushort4*)o4;
      }
  }
#undef DUMP
#undef ACCUM
}

extern "C" void kernel_launch(void* const* d_in, const int* in_sizes, int n_in,
                              void* d_out, int out_size, void* d_ws, size_t ws_size,
                              hipStream_t stream) {
  const float* input = (const float*)d_in[0];
  const float* w_qkv = (const float*)d_in[1];
  const float* b_qkv = (const float*)d_in[2];
  const float* q_scale = (const float*)d_in[3];
  const float* k_scale = (const float*)d_in[4];
  const float* w_out = (const float*)d_in[5];
  const float* b_out = (const float*)d_in[6];
  float* out = (float*)d_out;

  char* ws = (char*)d_ws;
  u16* Abuf  = (u16*)(ws);                // 4096x1024 bf16
  u16* WqkvT = (u16*)(ws + 8388608);      // 3072x1024 bf16
  u16* WoutT = (u16*)(ws + 14680064);     // 1024x1024 bf16
  u16* qkv   = (u16*)(ws + 16777216);     // 4096x3072 bf16
  u16* Qb    = (u16*)(ws + 41943040);     // [32][2048][64] bf16
  u16* Kb    = (u16*)(ws + 50331648);     // [32][2048][64] bf16
  u16* Vt    = (u16*)(ws + 58720256);     // [32][64][2048] bf16
  u16* Attn  = (u16*)(ws + 67108864);     // 4096x1024 bf16
  float2* Rt = (float2*)(ws + 75497472);  // [2048][32] float2 (512 KB)

  k_prep<<<4352, 256, 0, stream>>>(input, Abuf, w_qkv, WqkvT, w_out, WoutT, Rt);
  k_gemm<1><<<dim3(32, 24), 256, 0, stream>>>(Abuf, WqkvT, b_qkv, qkv, 4096, 3072, 1024);
  k_nv<<<5120, 256, 0, stream>>>(qkv, q_scale, k_scale, Rt, Qb, Kb, Vt);
  k_attn<<<dim3(32, 32), 512, 0, stream>>>(Qb, Kb, Vt, Attn);
  k_gemm<0><<<dim3(32, 8), 256, 0, stream>>>(Attn, WoutT, b_out, out, 4096, 1024, 1024);
}

// Round 16
// 122.097 us; speedup vs baseline: 1.1301x; 1.1301x over previous
//
#include <hip/hip_runtime.h>
#include <stdint.h>

typedef short bf16x8 __attribute__((ext_vector_type(8)));
typedef float f32x4 __attribute__((ext_vector_type(4)));
typedef float f32x16 __attribute__((ext_vector_type(16)));
typedef unsigned short u16;

#define MFMA_BF16 __builtin_amdgcn_mfma_f32_16x16x32_bf16
#define MFMA32 __builtin_amdgcn_mfma_f32_32x32x16_bf16
#define LOG2E 1.44269504088896f

#if __has_builtin(__builtin_amdgcn_exp2f)
#define EXP2(x) __builtin_amdgcn_exp2f(x)
#else
#define EXP2(x) exp2f(x)
#endif

static __device__ __forceinline__ u16 f2bf(float x) {
  union { float f; unsigned u; } v; v.f = x;
  unsigned r = v.u + 0x7fffu + ((v.u >> 16) & 1u);
  return (u16)(r >> 16);
}
static __device__ __forceinline__ float bf2f(u16 h) {
  union { unsigned u; float f; } v; v.u = ((unsigned)h) << 16; return v.f;
}
static __device__ __forceinline__ unsigned cvt_pk_bf16(float lo, float hi) {
  unsigned r;
  asm("v_cvt_pk_bf16_f32 %0, %1, %2" : "=v"(r) : "v"(lo), "v"(hi));
  return r;
}
static __device__ __forceinline__ void gld_lds16(const u16* g, u16* l) {
  __builtin_amdgcn_global_load_lds(
      (const __attribute__((address_space(1))) void*)g,
      (__attribute__((address_space(3))) void*)l, 16, 0, 0);
}

// ---------------- fused prep: cast | wtrans(w_qkv) | wtrans(w_out) | ropetab ----------------
// Block-range dispatch; bodies identical to the previous separate kernels.
__global__ __launch_bounds__(256) void k_prep(const float* __restrict__ x,
                                              u16* __restrict__ y,
                                              const float* __restrict__ wqkv,
                                              u16* __restrict__ wqkvT,
                                              const float* __restrict__ wout,
                                              u16* __restrict__ woutT,
                                              float2* __restrict__ tab) {
  const int bid = blockIdx.x;
  const int tid = threadIdx.x;
  if (bid < 2048) {
    // cast fp32 -> bf16, 8 elems/thread
    int i = bid * 256 + tid;
    const float4* p = (const float4*)x;
    float4 a = p[i * 2], b = p[i * 2 + 1];
    ushort4 o0, o1;
    o0.x = f2bf(a.x); o0.y = f2bf(a.y); o0.z = f2bf(a.z); o0.w = f2bf(a.w);
    o1.x = f2bf(b.x); o1.y = f2bf(b.y); o1.z = f2bf(b.z); o1.w = f2bf(b.w);
    ushort4* q = (ushort4*)y;
    q[i * 2] = o0; q[i * 2 + 1] = o1;
  } else if (bid < 3584) {
    // w_qkv transpose: K=1024, N=3072 (12 x-blocks x 128 y-blocks)
    int r = bid - 2048;
    int n = (r % 12) * 256 + tid;
    int k0 = (r / 12) * 8;
    u16 o[8];
#pragma unroll
    for (int j = 0; j < 8; j++) o[j] = f2bf(wqkv[(size_t)(k0 + j) * 3072 + n]);
    *(uint4*)&wqkvT[(size_t)n * 1024 + k0] = *(const uint4*)o;
  } else if (bid < 4096) {
    // w_out transpose: K=1024, N=1024 (4 x-blocks x 128 y-blocks)
    int r = bid - 3584;
    int n = (r % 4) * 256 + tid;
    int k0 = (r / 4) * 8;
    u16 o[8];
#pragma unroll
    for (int j = 0; j < 8; j++) o[j] = f2bf(wout[(size_t)(k0 + j) * 1024 + n]);
    *(uint4*)&woutT[(size_t)n * 1024 + k0] = *(const uint4*)o;
  } else {
    // rope table: tab[n][f] = {cos, sin}
    int i = (bid - 4096) * 256 + tid;  // 65536 = 2048*32
    int n = i >> 5, f = i & 31;
    float inv = exp2f(-(float)f * (13.287712379549449f / 32.f));
    float fr = (float)n * inv;
    float s, c;
    sincosf(fr, &s, &c);
    float2 cs; cs.x = c; cs.y = s;
    tab[i] = cs;
  }
}

// ---------------- GEMM: C[M][N] = A[M][K] * Bt[N][K]^T + bias (R9 form) ----------------
template <int OUT_BF16>
__global__ __launch_bounds__(256, 2) void k_gemm(const u16* __restrict__ A,
                                                 const u16* __restrict__ Bt,
                                                 const float* __restrict__ bias,
                                                 void* __restrict__ Cp,
                                                 int M, int N, int K) {
  __shared__ u16 As[128 * 64];
  __shared__ u16 Bs[128 * 64];
  const int tid = threadIdx.x;
  const int lane = tid & 63;
  const int wid = tid >> 6;
  const int wm = wid >> 1, wn = wid & 1;
  const int m0 = blockIdx.x * 128, n0 = blockIdx.y * 128;

  const int sr = tid >> 3;
  const int sc = tid & 7;
  const int scsw = sc ^ (sr & 7);
  const u16* ga = A + (size_t)(m0 + sr) * K + (scsw << 3);
  const u16* gb = Bt + (size_t)(n0 + sr) * K + (scsw << 3);

  const int ar = wm * 64 + (lane & 15);
  const int br = wn * 64 + (lane & 15);
  const int cs0 = lane >> 4;

  f32x4 acc[4][4] = {};

  for (int k0 = 0; k0 < K; k0 += 64) {
    __syncthreads();
#pragma unroll
    for (int i = 0; i < 4; i++)
      gld_lds16(ga + k0 + i * (32 * K), &As[((tid & ~63) + 256 * i) * 8]);
#pragma unroll
    for (int i = 0; i < 4; i++)
      gld_lds16(gb + k0 + i * (32 * K), &Bs[((tid & ~63) + 256 * i) * 8]);
    __syncthreads();
#pragma unroll
    for (int kk = 0; kk < 2; kk++) {
      bf16x8 af[4], bfr[4];
#pragma unroll
      for (int mi = 0; mi < 4; mi++)
        af[mi] = *(const bf16x8*)&As[(ar + mi * 16) * 64 +
                                     (((kk * 4 + cs0) ^ (ar & 7)) << 3)];
#pragma unroll
      for (int ni = 0; ni < 4; ni++)
        bfr[ni] = *(const bf16x8*)&Bs[(br + ni * 16) * 64 +
                                      (((kk * 4 + cs0) ^ (br & 7)) << 3)];
#pragma unroll
      for (int mi = 0; mi < 4; mi++)
#pragma unroll
        for (int ni = 0; ni < 4; ni++)
          acc[mi][ni] = MFMA_BF16(af[mi], bfr[ni], acc[mi][ni], 0, 0, 0);
    }
  }

  const int crow0 = m0 + wm * 64 + ((lane >> 4) << 2);
  const int ccol0 = n0 + wn * 64 + (lane & 15);
#pragma unroll
  for (int ni = 0; ni < 4; ni++) {
    float bv = bias[ccol0 + ni * 16];
#pragma unroll
    for (int mi = 0; mi < 4; mi++) {
#pragma unroll
      for (int r = 0; r < 4; r++) {
        float v = acc[mi][ni][r] + bv;
        size_t idx = (size_t)(crow0 + mi * 16 + r) * N + ccol0 + ni * 16;
        if (OUT_BF16) ((u16*)Cp)[idx] = f2bf(v);
        else ((float*)Cp)[idx] = v;
      }
    }
  }
}

// ---------------- fused norm/rope + v-transpose ----------------
// blocks [0,4096): RMSNorm+RoPE row kernel; blocks [4096,5120): V transpose.
__global__ __launch_bounds__(256) void k_nv(const u16* __restrict__ qkv,
                                            const float* __restrict__ qscale,
                                            const float* __restrict__ kscale,
                                            const float2* __restrict__ tab,
                                            u16* __restrict__ Qb,
                                            u16* __restrict__ Kb,
                                            u16* __restrict__ Vt) {
  __shared__ __align__(16) u16 sm[64 * 72];  // 18.4 KB union
  const int t = threadIdx.x;
  if (blockIdx.x < 4096) {
    const int row = blockIdx.x;  // b*2048+n
    const int b = row >> 11, n = row & 2047;
    float* qn = (float*)sm;            // [1024]
    float* kn = qn + 1024;             // [1024]
    __shared__ float redq[4], redk[4];

    ushort4 q4 = *(const ushort4*)&qkv[(size_t)row * 3072 + t * 4];
    ushort4 k4 = *(const ushort4*)&qkv[(size_t)row * 3072 + 1024 + t * 4];
    float qv[4] = {bf2f(q4.x), bf2f(q4.y), bf2f(q4.z), bf2f(q4.w)};
    float kv[4] = {bf2f(k4.x), bf2f(k4.y), bf2f(k4.z), bf2f(k4.w)};
    float sq = 0.f, sk = 0.f;
#pragma unroll
    for (int j = 0; j < 4; j++) { sq += qv[j] * qv[j]; sk += kv[j] * kv[j]; }
#pragma unroll
    for (int o = 1; o < 64; o <<= 1) {
      sq += __shfl_xor(sq, o);
      sk += __shfl_xor(sk, o);
    }
    if ((t & 63) == 0) { redq[t >> 6] = sq; redk[t >> 6] = sk; }

    const int j0 = t * 4;
    const int d0 = j0 & 63;
    float2 cs[4];
    {
      const float2* tb = tab + n * 32 + (d0 & 31);
      *(float4*)&cs[0] = *(const float4*)&tb[0];
      *(float4*)&cs[2] = *(const float4*)&tb[2];
    }
    __syncthreads();
    float rq = rsqrtf((redq[0] + redq[1] + redq[2] + redq[3]) * (1.f / 1024.f) + 1e-6f);
    float rk = rsqrtf((redk[0] + redk[1] + redk[2] + redk[3]) * (1.f / 1024.f) + 1e-6f);
#pragma unroll
    for (int j = 0; j < 4; j++) {
      int jj = t * 4 + j;
      qn[jj] = qv[j] * rq * qscale[jj];
      kn[jj] = kv[j] * rk * kscale[jj];
    }
    __syncthreads();
    const int h = j0 >> 6;
    u16 qo[4], ko[4];
#pragma unroll
    for (int j = 0; j < 4; j++) {
      int jj = j0 + j;
      int dd = d0 + j;
      float c = cs[j].x, s = cs[j].y;
      float oq, ok;
      if (dd < 32) {
        oq = qn[jj] * c - qn[jj + 32] * s;
        ok = kn[jj] * c - kn[jj + 32] * s;
      } else {
        oq = qn[jj] * c + qn[jj - 32] * s;
        ok = kn[jj] * c + kn[jj - 32] * s;
      }
      qo[j] = f2bf(oq * (0.125f * LOG2E));  // logit scale * log2e
      ko[j] = f2bf(ok);
    }
    const size_t base = ((size_t)(b * 16 + h) * 2048 + n) * 64 + d0;
    *(ushort4*)&Qb[base] = *(const ushort4*)qo;
    *(ushort4*)&Kb[base] = *(const ushort4*)ko;
  } else {
    const int r = blockIdx.x - 4096;
    const int bh = r >> 5;
    const int b = bh >> 4, h = bh & 15;
    const int n0 = (r & 31) * 64;
    u16 (*tile)[72] = (u16(*)[72])sm;
#pragma unroll
    for (int i = 0; i < 2; i++) {
      int rr = (t >> 3) + 32 * i;
      int c = t & 7;
      uint4 v = *(const uint4*)&qkv[((size_t)(b * 2048 + n0 + rr)) * 3072 + 2048 + h * 64 + c * 8];
      *(uint4*)&tile[rr][c * 8] = v;
    }
    __syncthreads();
#pragma unroll
    for (int i = 0; i < 2; i++) {
      int dr = (t >> 3) + 32 * i;
      int c = t & 7;
      u16 vals[8];
#pragma unroll
      for (int j = 0; j < 8; j++) vals[j] = tile[c * 8 + j][dr];
      *(uint4*)&Vt[((size_t)bh * 64 + dr) * 2048 + n0 + c * 8] = *(const uint4*)vals;
    }
  }
}

// ---------------- flash attention (v9 form: interleaved chains) ----------------
__global__ __launch_bounds__(512, 4) void k_attn(const u16* __restrict__ Qb,
                                                 const u16* __restrict__ Kb,
                                                 const u16* __restrict__ Vt,
                                                 u16* __restrict__ Ob) {
  const int bh = blockIdx.y;
  const int q0 = blockIdx.x * 128;
  const int t = threadIdx.x, lane = t & 63, wid = t >> 6;
  const int grp = wid >> 2, sub = wid & 3;
  const int q = lane & 31, hi = lane >> 5;

  __shared__ u16 smem[32768];              // 64 KB: Ks[4][4096] | Vs[4][4096]
  u16* Ks = smem;
  u16* Vs = smem + 4 * 4096;

  const u16* Qg = Qb + (size_t)bh * 2048 * 64;
  const u16* Kg = Kb + (size_t)bh * 2048 * 64;
  const u16* Vg = Vt + (size_t)bh * 64 * 2048;

  bf16x8 qf[4];
  {
    const u16* qrow = Qg + (size_t)(q0 + sub * 32 + q) * 64;
#pragma unroll
    for (int kk = 0; kk < 4; kk++)
      qf[kk] = *(const bf16x8*)&qrow[kk * 16 + hi * 8];
  }

  f32x16 ot[2] = {};
  float lacc[4] = {0.f, 0.f, 0.f, 0.f};

  const int srow = t >> 3;
  const int sslot = (t & 7) ^ (srow & 7);
  const u16* gk = Kg + srow * 64 + (sslot << 3);
  const u16* gv = Vg + (size_t)srow * 2048 + (sslot << 3);
  const int ldoff = (t & ~63) * 8;

#define STAGE(tile)                                                     \
  do {                                                                  \
    gld_lds16(gk + (size_t)(tile) * 4096, &Ks[((tile) & 3) * 4096 + ldoff]); \
    gld_lds16(gv + (size_t)(tile) * 64,   &Vs[((tile) & 3) * 4096 + ldoff]); \
  } while (0)

  STAGE(0); STAGE(1); STAGE(2); STAGE(3);

  for (int s = 0; s < 16; ++s) {
    if (s < 15) asm volatile("s_waitcnt vmcnt(4)" ::: "memory");
    else        asm volatile("s_waitcnt vmcnt(0)" ::: "memory");
    asm volatile("s_barrier" ::: "memory");

    const int myt = 2 * s + grp;
    const u16* Kc = &Ks[(myt & 3) * 4096];
    const u16* Vc = &Vs[(myt & 3) * 4096];

    f32x16 sv0 = {}, sv1 = {};
#pragma unroll
    for (int kk = 0; kk < 4; kk++) {
      const int kr0 = q;
      const int kr1 = 32 + q;
      bf16x8 kf0 = *(const bf16x8*)&Kc[kr0 * 64 + (((kk * 2 + hi) ^ (kr0 & 7)) << 3)];
      bf16x8 kf1 = *(const bf16x8*)&Kc[kr1 * 64 + (((kk * 2 + hi) ^ (kr1 & 7)) << 3)];
      __builtin_amdgcn_s_setprio(1);
      sv0 = MFMA32(kf0, qf[kk], sv0, 0, 0, 0);
      sv1 = MFMA32(kf1, qf[kk], sv1, 0, 0, 0);
      __builtin_amdgcn_s_setprio(0);
    }

    unsigned w[2][8];
#pragma unroll
    for (int i = 0; i < 8; i++) {
      float p0 = EXP2(sv0[2 * i]);
      float p1 = EXP2(sv0[2 * i + 1]);
      lacc[i & 3] += p0 + p1;
      w[0][i] = cvt_pk_bf16(p0, p1);
    }
#pragma unroll
    for (int i = 0; i < 8; i++) {
      float p0 = EXP2(sv1[2 * i]);
      float p1 = EXP2(sv1[2 * i + 1]);
      lacc[i & 3] += p0 + p1;
      w[1][i] = cvt_pk_bf16(p0, p1);
    }

#pragma unroll
    for (int ks = 0; ks < 4; ks++) {
      const int kvt = ks >> 1, i0 = (ks & 1) * 4;
      unsigned xs0 = hi ? w[kvt][i0 + 0] : w[kvt][i0 + 2];
      unsigned xs1 = hi ? w[kvt][i0 + 1] : w[kvt][i0 + 3];
      unsigned y0 = __shfl_xor(xs0, 32);
      unsigned y1 = __shfl_xor(xs1, 32);
      union { unsigned u[4]; bf16x8 v; } pf;
      pf.u[0] = hi ? y0 : w[kvt][i0 + 0];
      pf.u[1] = hi ? y1 : w[kvt][i0 + 1];
      pf.u[2] = hi ? w[kvt][i0 + 2] : y0;
      pf.u[3] = hi ? w[kvt][i0 + 3] : y1;
#pragma unroll
      for (int dt = 0; dt < 2; dt++) {
        const int vr = dt * 32 + q;
        bf16x8 va = *(const bf16x8*)&Vc[vr * 64 + (((ks * 2 + hi) ^ (vr & 7)) << 3)];
        __builtin_amdgcn_s_setprio(1);
        ot[dt] = MFMA32(va, pf.v, ot[dt], 0, 0, 0);
        __builtin_amdgcn_s_setprio(0);
      }
    }

    asm volatile("s_barrier" ::: "memory");
    if (s < 14) { STAGE(2 * s + 4); STAGE(2 * s + 5); }
  }
#undef STAGE

  float lsum = (lacc[0] + lacc[1]) + (lacc[2] + lacc[3]);
  lsum += __shfl_xor(lsum, 32);
  __syncthreads();
  float* obuf = (float*)smem;                  // [4][32 q][64 d] = 32 KB
  float* lbuf = (float*)(smem + 16384);        // [4][32]
  if (grp == 1) {
    float* ob = obuf + (sub * 32 + q) * 64;
#pragma unroll
    for (int dt = 0; dt < 2; dt++)
#pragma unroll
      for (int g = 0; g < 4; g++) {
        float4 v4 = {ot[dt][4 * g], ot[dt][4 * g + 1], ot[dt][4 * g + 2], ot[dt][4 * g + 3]};
        *(float4*)&ob[dt * 32 + 8 * g + 4 * hi] = v4;
      }
    if (hi == 0) lbuf[sub * 32 + q] = lsum;
  }
  __syncthreads();
  if (grp == 0) {
    const float* ob = obuf + (sub * 32 + q) * 64;
    const float invl = 1.f / (lsum + lbuf[sub * 32 + q]);
    const int b = bh >> 4, h = bh & 15;
    const int rowq = q0 + sub * 32 + q;
    u16* orow = Ob + (size_t)(b * 2048 + rowq) * 1024 + h * 64;
#pragma unroll
    for (int dt = 0; dt < 2; dt++)
#pragma unroll
      for (int g = 0; g < 4; g++) {
        float4 v4 = *(const float4*)&ob[dt * 32 + 8 * g + 4 * hi];
        u16 o4[4];
        o4[0] = f2bf((ot[dt][4 * g + 0] + v4.x) * invl);
        o4[1] = f2bf((ot[dt][4 * g + 1] + v4.y) * invl);
        o4[2] = f2bf((ot[dt][4 * g + 2] + v4.z) * invl);
        o4[3] = f2bf((ot[dt][4 * g + 3] + v4.w) * invl);
        *(ushort4*)&orow[dt * 32 + 8 * g + 4 * hi] = *(const ushort4*)o4;
      }
  }
}

extern "C" void kernel_launch(void* const* d_in, const int* in_sizes, int n_in,
                              void* d_out, int out_size, void* d_ws, size_t ws_size,
                              hipStream_t stream) {
  const float* input = (const float*)d_in[0];
  const float* w_qkv = (const float*)d_in[1];
  const float* b_qkv = (const float*)d_in[2];
  const float* q_scale = (const float*)d_in[3];
  const float* k_scale = (const float*)d_in[4];
  const float* w_out = (const float*)d_in[5];
  const float* b_out = (const float*)d_in[6];
  float* out = (float*)d_out;

  char* ws = (char*)d_ws;
  u16* Abuf  = (u16*)(ws);                // 4096x1024 bf16
  u16* WqkvT = (u16*)(ws + 8388608);      // 3072x1024 bf16
  u16* WoutT = (u16*)(ws + 14680064);     // 1024x1024 bf16
  u16* qkv   = (u16*)(ws + 16777216);     // 4096x3072 bf16
  u16* Qb    = (u16*)(ws + 41943040);     // [32][2048][64] bf16
  u16* Kb    = (u16*)(ws + 50331648);     // [32][2048][64] bf16
  u16* Vt    = (u16*)(ws + 58720256);     // [32][64][2048] bf16
  u16* Attn  = (u16*)(ws + 67108864);     // 4096x1024 bf16
  float2* Rt = (float2*)(ws + 75497472);  // [2048][32] float2 (512 KB)

  k_prep<<<4352, 256, 0, stream>>>(input, Abuf, w_qkv, WqkvT, w_out, WoutT, Rt);
  k_gemm<1><<<dim3(32, 24), 256, 0, stream>>>(Abuf, WqkvT, b_qkv, qkv, 4096, 3072, 1024);
  k_nv<<<5120, 256, 0, stream>>>(qkv, q_scale, k_scale, Rt, Qb, Kb, Vt);
  k_attn<<<dim3(16, 32), 512, 0, stream>>>(Qb, Kb, Vt, Attn);
  k_gemm<0><<<dim3(32, 8), 256, 0, stream>>>(Attn, WoutT, b_out, out, 4096, 1024, 1024);
}